// Round 10
// baseline (1209.132 us; speedup 1.0000x reference)
//
#include <hip/hip_runtime.h>

#define NB   8
#define NPTS 4096
#define NS   1024
#define NF   64

typedef __bf16 bf16x8 __attribute__((ext_vector_type(8)));
typedef float  f32x4  __attribute__((ext_vector_type(4)));
typedef unsigned long long ullx2 __attribute__((ext_vector_type(2)));

// ---------------------------------------------------------------------------
// Weight prep: pack fp32 (CO,CI) row-major weights into MFMA B-fragment
// layout for mfma_f32_16x16x32_bf16 (see wave_layer).
// ---------------------------------------------------------------------------
struct WPrep {
  const float* src[9];
  int CO[9], CI[9], KC[9], off[9];
};

__global__ __launch_bounds__(256) void wprep_kernel(WPrep a, __bf16* __restrict__ dst) {
  const int id = blockIdx.y;
  const int t  = blockIdx.x * 256 + threadIdx.x;
  const int CT = a.CO[id] >> 4;
  const int KC = a.KC[id], CI = a.CI[id];
  if (t >= CT * KC * 64) return;
  const int lane = t & 63;
  const int fidx = t >> 6;
  const int kc = fidx % KC;
  const int ct = fidx / KC;
  const int n  = ct * 16 + (lane & 15);
  const int k0 = kc * 32 + (lane >> 4) * 8;
  const float* src = a.src[id];
  __bf16* d = dst + a.off[id] + (size_t)t * 8;
#pragma unroll
  for (int j = 0; j < 8; ++j) {
    const int k = k0 + j;
    d[j] = (__bf16)((k < CI) ? src[n * CI + k] : 0.0f);
  }
}

// ---------------------------------------------------------------------------
// Point prep: (x,y,z) -> (x,y,z,|p|^2) float4, norm with the exact _rn chain
// group_kernel uses (bit-identical sqd downstream).
// ---------------------------------------------------------------------------
__global__ __launch_bounds__(256) void pts_prep(const float* __restrict__ xyz,
                                                float4* __restrict__ pts4) {
  const int i = blockIdx.x * 256 + threadIdx.x;
  if (i >= NB * NPTS) return;
  const float x = xyz[i * 3 + 0], y = xyz[i * 3 + 1], z = xyz[i * 3 + 2];
  const float sp = __fadd_rn(__fadd_rn(__fmul_rn(x, x), __fmul_rn(y, y)),
                             __fmul_rn(z, z));
  pts4[i] = make_float4(x, y, z, sp);
}

// ---------------------------------------------------------------------------
// Farthest point sampling v8. One 256-thread block per batch. Bit-exact vs
// numpy: _rn expression tree, first-max tie-breaking.
// R7-R9 post-mortem: float arrays px[16]/py[16]/pz[16]/dist[16] were never
// SROA-promoted -- they lived in scratch/memory and every iteration re-loaded
// them (cached, so invisible in FETCH_SIZE; VGPR stuck at 48; "+v" asm pins
// just added load/store round trips). v8 uses 64 NAMED SCALARS (macro-
// generated) -- scalars are SSA by construction, and with launch_bounds(256,1)
// there is no pressure to spill ~90 live regs against a ~512 budget. Init
// from LDS staging so any residual remat is ds_read (R6-class), not scratch.
//   - contiguous mapping: lane l owns [16l,16l+16), wave w owns [1024w,..).
//   - winner COORDS tracked inline (cndmask on strict >), no index ever:
//     in-lane first-max = forward strict >, cross-lane = ballot+ffs,
//     cross-wave = key low bits 3-wid.
//   - winner lane writes {key, wx,wy,wz}; ONE barrier; all threads read
//     keys[4]+xs[4]+ys[4]+zs[4] as 5 independent b128 loads (one latency),
//     3 u64 maxes, cndmask coord select. Records parity double-buffered.
// ---------------------------------------------------------------------------
template <int CTRL>
__device__ __forceinline__ float dpp_fmax_step(float v) {
  const int t = __builtin_amdgcn_update_dpp(0, __float_as_int(v), CTRL, 0xf, 0xf, true);
  return fmaxf(v, __int_as_float(t));
}

__global__ __launch_bounds__(256, 1) void fps_kernel(const float4* __restrict__ pts4,
                                                     float* __restrict__ new_xyz) {
  const int b   = blockIdx.x;
  const int tid = threadIdx.x;
  __shared__ float sx[NPTS], sy[NPTS], sz[NPTS];
  __shared__ alignas(16) unsigned long long s_keys[8];  // [parity*4 + wave]
  __shared__ alignas(16) float s_xs[8], s_ys[8], s_zs[8];

  const float4* pb = pts4 + (size_t)b * NPTS;
  for (int p = tid; p < NPTS; p += 256) {
    const float4 P = pb[p];
    sx[p] = P.x; sy[p] = P.y; sz[p] = P.z;
  }
  __syncthreads();

  const int base = tid * 16;   // contiguous: lane order = index order
#define DECLP(i)                                                               \
  float px##i = sx[base + i], py##i = sy[base + i], pz##i = sz[base + i],      \
        dd##i = 1e10f;
  DECLP(0) DECLP(1) DECLP(2) DECLP(3) DECLP(4) DECLP(5) DECLP(6) DECLP(7)
  DECLP(8) DECLP(9) DECLP(10) DECLP(11) DECLP(12) DECLP(13) DECLP(14) DECLP(15)
#undef DECLP

  float cx = sx[0], cy = sy[0], cz = sz[0];
  const int wid  = tid >> 6;
  const int lane = tid & 63;
  for (int j = 0; j < NS; ++j) {
    if (tid == 0) {
      float* o = new_xyz + ((size_t)b * NS + j) * 3;
      o[0] = cx; o[1] = cy; o[2] = cz;
    }
    float bv = -1.0f, wx = 0.0f, wy = 0.0f, wz = 0.0f;
    // forward scan, strict > : keeps FIRST (smallest-index) max; coords
    // tracked by the same predicate -- no index register needed.
#define STEP(i)                                                                \
  {                                                                            \
    const float dx = __fsub_rn(px##i, cx);                                     \
    const float dy = __fsub_rn(py##i, cy);                                     \
    const float dz = __fsub_rn(pz##i, cz);                                     \
    const float d  = __fadd_rn(__fadd_rn(__fmul_rn(dx, dx), __fmul_rn(dy, dy)),\
                               __fmul_rn(dz, dz));                             \
    const float nd = fminf(dd##i, d);                                          \
    dd##i = nd;                                                                \
    const bool m = nd > bv;                                                    \
    bv = m ? nd : bv;                                                          \
    wx = m ? px##i : wx;                                                       \
    wy = m ? py##i : wy;                                                       \
    wz = m ? pz##i : wz;                                                       \
  }
    STEP(0) STEP(1) STEP(2) STEP(3) STEP(4) STEP(5) STEP(6) STEP(7)
    STEP(8) STEP(9) STEP(10) STEP(11) STEP(12) STEP(13) STEP(14) STEP(15)
#undef STEP
    // wave max via DPP (VALU-latency chain, no DS unit)
    float v = bv;
    v = dpp_fmax_step<0x111>(v);   // row_shr:1
    v = dpp_fmax_step<0x112>(v);   // row_shr:2
    v = dpp_fmax_step<0x114>(v);   // row_shr:4
    v = dpp_fmax_step<0x118>(v);   // row_shr:8
    v = dpp_fmax_step<0x142>(v);   // row_bcast:15
    v = dpp_fmax_step<0x143>(v);   // row_bcast:31
    const float wmax = __int_as_float(
        __builtin_amdgcn_readlane(__float_as_int(v), 63));
    const unsigned long long cand = __ballot(bv == wmax);
    const int fl = (int)__ffsll((long long)cand) - 1;  // lowest lane = smallest idx
    const int par = (j & 1) * 4;
    if (lane == fl) {
      // key: value bits high, (3-wid) low -> u64 max picks max value, then
      // smallest wave id (contiguous map => smallest global index).
      s_keys[par + wid] = ((unsigned long long)__float_as_uint(wmax) << 32) |
                          (unsigned)(3 - wid);
      s_xs[par + wid] = wx;
      s_ys[par + wid] = wy;
      s_zs[par + wid] = wz;
    }
    __syncthreads();
    // one latency batch: 5 independent 16B LDS loads
    const ullx2 ka = *(const ullx2*)(s_keys + par);
    const ullx2 kb = *(const ullx2*)(s_keys + par + 2);
    const float4 xs4 = *(const float4*)(s_xs + par);
    const float4 ys4 = *(const float4*)(s_ys + par);
    const float4 zs4 = *(const float4*)(s_zs + par);
    unsigned long long k = ka.x;
    if (ka.y > k) k = ka.y;
    if (kb.x > k) k = kb.x;
    if (kb.y > k) k = kb.y;
    const int ws = 3 - (int)(k & 3ull);
    cx = (ws == 0) ? xs4.x : (ws == 1) ? xs4.y : (ws == 2) ? xs4.z : xs4.w;
    cy = (ws == 0) ? ys4.x : (ws == 1) ? ys4.y : (ws == 2) ? ys4.z : ys4.w;
    cz = (ws == 0) ? zs4.x : (ws == 1) ? zs4.y : (ws == 2) ? zs4.z : zs4.w;
  }
}

// ---------------------------------------------------------------------------
// Ball grouping, all three radii in one index-ordered scan. One wave per (b,s).
// Reads precomputed (x,y,z,|p|^2) float4: one coalesced 16B load per point.
// ---------------------------------------------------------------------------
__global__ __launch_bounds__(64) void group_kernel(
    const float4* __restrict__ pts4, const float* __restrict__ new_xyz,
    int* __restrict__ nbr0, int* __restrict__ nbr1, int* __restrict__ nbr2,
    int* __restrict__ cnt0, int* __restrict__ cnt1, int* __restrict__ cnt2) {
  const int bs   = blockIdx.x;
  const int b    = bs >> 10;
  const int lane = threadIdx.x;
  const float r2_0 = (float)(0.1 * 0.1);
  const float r2_1 = (float)(0.2 * 0.2);
  const float r2_2 = (float)(0.4 * 0.4);

  const float cx = new_xyz[bs * 3 + 0];
  const float cy = new_xyz[bs * 3 + 1];
  const float cz = new_xyz[bs * 3 + 2];
  const float sn = __fadd_rn(__fadd_rn(__fmul_rn(cx, cx), __fmul_rn(cy, cy)),
                             __fmul_rn(cz, cz));
  const float4* pb = pts4 + (size_t)b * NPTS;
  const unsigned long long below = (1ull << lane) - 1ull;

  int c0 = 0, c1 = 0, c2 = 0;
  for (int base = 0; base < NPTS; base += 64) {
    const int p = base + lane;
    const float4 P = pb[p];
    const float dt = __fadd_rn(__fadd_rn(__fmul_rn(cx, P.x), __fmul_rn(cy, P.y)),
                               __fmul_rn(cz, P.z));
    const float sqd = __fsub_rn(__fadd_rn(sn, P.w), __fmul_rn(2.0f, dt));
    const bool in0 = (sqd <= r2_0);
    const bool in1 = (sqd <= r2_1);
    const bool in2 = (sqd <= r2_2);
    const unsigned long long m0 = __ballot(in0);
    const unsigned long long m1 = __ballot(in1);
    const unsigned long long m2 = __ballot(in2);
    if (c0 < 16) {
      const int slot = c0 + __popcll(m0 & below);
      if (in0 && slot < 16) nbr0[bs * 16 + slot] = p;
      c0 = min(c0 + __popcll(m0), 16);
    }
    if (c1 < 32) {
      const int slot = c1 + __popcll(m1 & below);
      if (in1 && slot < 32) nbr1[bs * 32 + slot] = p;
      c1 = min(c1 + __popcll(m1), 32);
    }
    if (c2 < 128) {
      const int slot = c2 + __popcll(m2 & below);
      if (in2 && slot < 128) nbr2[bs * 128 + slot] = p;
      c2 = min(c2 + __popcll(m2), 128);
    }
    if (c0 == 16 && c1 == 32 && c2 == 128) break;
  }
  if (lane == 0) {
    cnt0[bs] = c0;
    cnt1[bs] = c1;
    cnt2[bs] = c2;
  }
}

// ---------------------------------------------------------------------------
// One layer for one wave: RT row-tiles (16 rows each) x all CO cols, K-chunks
// of 32. A from LDS (rows = this wave's neighbors), B fragments from global
// (pre-packed). Non-last: relu -> bf16 LDS store. Last: per-lane column max.
// ---------------------------------------------------------------------------
template <int RT, int KC, int CO, int SIN, int SOUT, bool LAST>
__device__ __forceinline__ void wave_layer(const __bf16* in, __bf16* outb,
                                           const __bf16* __restrict__ wf,
                                           const float* __restrict__ bias,
                                           int lane, float* colmax) {
  bf16x8 a[RT][KC];
#pragma unroll
  for (int rt = 0; rt < RT; ++rt)
#pragma unroll
    for (int kc = 0; kc < KC; ++kc)
      a[rt][kc] = *(const bf16x8*)(in + (rt * 16 + (lane & 15)) * SIN + kc * 32 +
                                   (lane >> 4) * 8);
#pragma unroll
  for (int ct = 0; ct < CO / 16; ++ct) {
    const float bv = bias[ct * 16 + (lane & 15)];
    bf16x8 bfr[KC];
#pragma unroll
    for (int kc = 0; kc < KC; ++kc)
      bfr[kc] = *(const bf16x8*)(wf + ((size_t)(ct * KC + kc) * 64 + lane) * 8);
    float cm = 0.0f;
#pragma unroll
    for (int rt = 0; rt < RT; ++rt) {
      f32x4 acc = {0.0f, 0.0f, 0.0f, 0.0f};
#pragma unroll
      for (int kc = 0; kc < KC; ++kc)
        acc = __builtin_amdgcn_mfma_f32_16x16x32_bf16(a[rt][kc], bfr[kc], acc, 0, 0, 0);
      if constexpr (!LAST) {
#pragma unroll
        for (int r = 0; r < 4; ++r) {
          const int row = rt * 16 + (lane >> 4) * 4 + r;
          const float v = fmaxf(acc[r] + bv, 0.0f);
          outb[row * SOUT + ct * 16 + (lane & 15)] = (__bf16)v;
        }
      } else {
#pragma unroll
        for (int r = 0; r < 4; ++r) cm = fmaxf(cm, acc[r] + bv);
      }
    }
    if constexpr (LAST) colmax[ct] = fmaxf(colmax[ct], cm);
  }
}

// ---------------------------------------------------------------------------
// Fused gather + 3-layer MFMA MLP + max-pool.
// WPP waves per point, PPB points per block. Row-slices are wave-private
// through gather/L1/L2/L3, so no barriers except the final cross-wave max
// (WPP>1 only; requires SH2==SX so h2 overlays the wave's own X rows).
// LDS row strides C+8 (stride%16==8 elems): 2-way bank alias only, 16B aligned.
// ---------------------------------------------------------------------------
template <int K, int C1, int C2, int C3, int WPP, int PPB>
__global__ __launch_bounds__(64 * WPP * PPB) void mlp_mfma(
    const float4* __restrict__ pts4, const float* __restrict__ feat,
    const float* __restrict__ new_xyz,
    const int* __restrict__ nbr, const int* __restrict__ cnt_arr,
    const __bf16* __restrict__ wf1, const float* __restrict__ b1,
    const __bf16* __restrict__ wf2, const float* __restrict__ b2,
    const __bf16* __restrict__ wf3, const float* __restrict__ b3,
    float* __restrict__ out, int ch_off) {
  constexpr int SX  = 104;           // 67 in-ch, zero-pad to 96, stride 104
  constexpr int SH1 = C1 + 8;
  constexpr int SH2 = C2 + 8;
  constexpr int KC1 = 3;
  constexpr int KC2 = C1 / 32;
  constexpr int KC3 = C2 / 32;
  constexpr int PT  = (104 + SH1) * K;   // region0 (X/h2 overlay) + region1 (h1)
  constexpr int MW  = K / WPP;
  constexpr int RT  = MW / 16;
  static_assert(WPP == 1 || SH2 == SX, "h2 overlay must match X rows for WPP>1");
  __shared__ __bf16 lds[PPB * PT];
  __shared__ float  red[(WPP > 1) ? WPP * C3 : 1];

  const int tid  = threadIdx.x;
  const int lane = tid & 63;
  const int wid  = tid >> 6;

  // ---- gather: stage X rows (3 rel coords + 64 feats + zero pad) as bf16 ----
  constexpr int TPN = (64 * WPP) / K;   // threads per neighbor (4, 2, 2)
  constexpr int FPT = NF / TPN;         // features per thread
  {
    const int ln = tid / TPN;
    const int s  = tid - ln * TPN;
    const int lp = ln / K;
    const int n  = ln - lp * K;
    const int p  = blockIdx.x * PPB + lp;
    const int b  = p >> 10;
    const int cnt = cnt_arr[p];
    const int idx = nbr[p * K + min(n, cnt - 1)];
    __bf16* Xr = lds + lp * PT + n * SX;
    const float4* fp4 = (const float4*)(feat + ((size_t)b * NPTS + idx) * NF + s * FPT);
#pragma unroll
    for (int j = 0; j < FPT / 4; ++j) {
      const float4 v = fp4[j];
      Xr[3 + s * FPT + 4 * j + 0] = (__bf16)v.x;
      Xr[3 + s * FPT + 4 * j + 1] = (__bf16)v.y;
      Xr[3 + s * FPT + 4 * j + 2] = (__bf16)v.z;
      Xr[3 + s * FPT + 4 * j + 3] = (__bf16)v.w;
    }
    if (s == 0) {
      const float4 P = pts4[(size_t)b * NPTS + idx];
      Xr[0] = (__bf16)(P.x - new_xyz[p * 3 + 0]);
      Xr[1] = (__bf16)(P.y - new_xyz[p * 3 + 1]);
      Xr[2] = (__bf16)(P.z - new_xyz[p * 3 + 2]);
#pragma unroll
      for (int k = 67; k < 96; ++k) Xr[k] = (__bf16)0.0f;
    }
  }

  // ---- per-wave 3-layer pipeline on its own row slice ----
  const int lpg = wid / WPP;
  const int wv  = wid - lpg * WPP;
  const int p   = blockIdx.x * PPB + lpg;
  const __bf16* X  = lds + lpg * PT + wv * MW * SX;
  __bf16*       H1 = lds + lpg * PT + K * 104 + wv * MW * SH1;
  __bf16*       H2 = lds + lpg * PT + wv * MW * SH2;

  float colmax[C3 / 16];
#pragma unroll
  for (int ct = 0; ct < C3 / 16; ++ct) colmax[ct] = 0.0f;

  wave_layer<RT, KC1, C1, SX, SH1, false>(X, H1, wf1, b1, lane, nullptr);
  wave_layer<RT, KC2, C2, SH1, SH2, false>(H1, H2, wf2, b2, lane, nullptr);
  wave_layer<RT, KC3, C3, SH2, 0, true>(H2, nullptr, wf3, b3, lane, colmax);

  // quad-reduce: combine the 4 row-quads of the wave
#pragma unroll
  for (int ct = 0; ct < C3 / 16; ++ct) {
    float v = colmax[ct];
    v = fmaxf(v, __shfl_xor(v, 16));
    v = fmaxf(v, __shfl_xor(v, 32));
    colmax[ct] = v;
  }

  if constexpr (WPP == 1) {
    if (lane < 16) {
      float* op = out + (size_t)p * 320 + ch_off;
#pragma unroll
      for (int ct = 0; ct < C3 / 16; ++ct) op[ct * 16 + lane] = colmax[ct];
    }
  } else {
    if (lane < 16) {
#pragma unroll
      for (int ct = 0; ct < C3 / 16; ++ct)
        red[wv * C3 + ct * 16 + lane] = colmax[ct];
    }
    __syncthreads();
    if (tid < C3) {
      float v = red[tid];
#pragma unroll
      for (int w = 1; w < WPP; ++w) v = fmaxf(v, red[w * C3 + tid]);
      out[(size_t)p * 320 + ch_off + tid] = v;
    }
  }
}

// ---------------------------------------------------------------------------
// Workspace (int units):
//   [0, 24576)          packed bf16 weight fragments (49152 bf16 = 98304 B)
//   [24576, 32768)      cnt0   [32768,40960) cnt1   [40960,49152) cnt2
//   [49152, 180224)     nbr0   [180224,442368) nbr1  [442368,1490944) nbr2
//   [1490944, 1622016)  pts4 (32768 x float4)        total ~6.49 MB
// ---------------------------------------------------------------------------
extern "C" void kernel_launch(void* const* d_in, const int* in_sizes, int n_in,
                              void* d_out, int out_size, void* d_ws, size_t ws_size,
                              hipStream_t stream) {
  const float* xyz  = (const float*)d_in[0];
  const float* feat = (const float*)d_in[1];
  float* out      = (float*)d_out;
  float* new_xyz  = out;
  float* feat_out = out + 24576;

  __bf16* wsb = (__bf16*)d_ws;
  int*    wsi = (int*)d_ws;

  // weight fragment offsets (bf16 elems)
  const int OW[9] = {0, 3072, 4096, 6144, 12288, 16384, 24576, 30720, 36864};
  const int widx[9] = {2, 4, 6, 8, 10, 12, 14, 16, 18};
  const int co[9] = {32, 32, 64, 64, 64, 128, 64, 96, 128};
  const int ci[9] = {67, 32, 32, 67, 64, 64, 67, 64, 96};
  const int kc[9] = {3, 1, 1, 3, 2, 2, 3, 2, 3};
  WPrep wp;
  for (int i = 0; i < 9; ++i) {
    wp.src[i] = (const float*)d_in[widx[i]];
    wp.CO[i] = co[i]; wp.CI[i] = ci[i]; wp.KC[i] = kc[i]; wp.off[i] = OW[i];
  }
  wprep_kernel<<<dim3(6, 9), 256, 0, stream>>>(wp, wsb);

  float4* pts4 = (float4*)(wsi + 1490944);
  pts_prep<<<(NB * NPTS + 255) / 256, 256, 0, stream>>>(xyz, pts4);

  fps_kernel<<<NB, 256, 0, stream>>>(pts4, new_xyz);

  int* cnt0 = wsi + 24576;
  int* cnt1 = wsi + 32768;
  int* cnt2 = wsi + 40960;
  int* nbr0 = wsi + 49152;
  int* nbr1 = wsi + 180224;
  int* nbr2 = wsi + 442368;
  group_kernel<<<NB * NS, 64, 0, stream>>>(pts4, new_xyz, nbr0, nbr1, nbr2,
                                           cnt0, cnt1, cnt2);

  mlp_mfma<16, 32, 32, 64, 1, 4><<<NB * NS / 4, 256, 0, stream>>>(
      pts4, feat, new_xyz, nbr0, cnt0,
      wsb + OW[0], (const float*)d_in[3],
      wsb + OW[1], (const float*)d_in[5],
      wsb + OW[2], (const float*)d_in[7],
      feat_out, 0);
  mlp_mfma<32, 64, 64, 128, 1, 2><<<NB * NS / 2, 128, 0, stream>>>(
      pts4, feat, new_xyz, nbr1, cnt1,
      wsb + OW[3], (const float*)d_in[9],
      wsb + OW[4], (const float*)d_in[11],
      wsb + OW[5], (const float*)d_in[13],
      feat_out, 64);
  mlp_mfma<128, 64, 96, 128, 4, 1><<<NB * NS, 256, 0, stream>>>(
      pts4, feat, new_xyz, nbr2, cnt2,
      wsb + OW[6], (const float*)d_in[15],
      wsb + OW[7], (const float*)d_in[17],
      wsb + OW[8], (const float*)d_in[19],
      feat_out, 192);
}

// Round 11
// 899.220 us; speedup vs baseline: 1.3446x; 1.3446x over previous
//
#include <hip/hip_runtime.h>

#define NB   8
#define NPTS 4096
#define NS   1024
#define NF   64

typedef __bf16 bf16x8 __attribute__((ext_vector_type(8)));
typedef float  f32x4  __attribute__((ext_vector_type(4)));
typedef unsigned long long ullx2 __attribute__((ext_vector_type(2)));

// ---------------------------------------------------------------------------
// Weight prep: pack fp32 (CO,CI) row-major weights into MFMA B-fragment
// layout for mfma_f32_16x16x32_bf16 (see wave_layer).
// ---------------------------------------------------------------------------
struct WPrep {
  const float* src[9];
  int CO[9], CI[9], KC[9], off[9];
};

__global__ __launch_bounds__(256) void wprep_kernel(WPrep a, __bf16* __restrict__ dst) {
  const int id = blockIdx.y;
  const int t  = blockIdx.x * 256 + threadIdx.x;
  const int CT = a.CO[id] >> 4;
  const int KC = a.KC[id], CI = a.CI[id];
  if (t >= CT * KC * 64) return;
  const int lane = t & 63;
  const int fidx = t >> 6;
  const int kc = fidx % KC;
  const int ct = fidx / KC;
  const int n  = ct * 16 + (lane & 15);
  const int k0 = kc * 32 + (lane >> 4) * 8;
  const float* src = a.src[id];
  __bf16* d = dst + a.off[id] + (size_t)t * 8;
#pragma unroll
  for (int j = 0; j < 8; ++j) {
    const int k = k0 + j;
    d[j] = (__bf16)((k < CI) ? src[n * CI + k] : 0.0f);
  }
}

// ---------------------------------------------------------------------------
// Point prep: (x,y,z) -> (x,y,z,|p|^2) float4, norm with the exact _rn chain
// group_kernel uses (bit-identical sqd downstream).
// ---------------------------------------------------------------------------
__global__ __launch_bounds__(256) void pts_prep(const float* __restrict__ xyz,
                                                float4* __restrict__ pts4) {
  const int i = blockIdx.x * 256 + threadIdx.x;
  if (i >= NB * NPTS) return;
  const float x = xyz[i * 3 + 0], y = xyz[i * 3 + 1], z = xyz[i * 3 + 2];
  const float sp = __fadd_rn(__fadd_rn(__fmul_rn(x, x), __fmul_rn(y, y)),
                             __fmul_rn(z, z));
  pts4[i] = make_float4(x, y, z, sp);
}

// ---------------------------------------------------------------------------
// Farthest point sampling v9. One 256-thread block per batch. Bit-exact vs
// numpy: _rn expression tree, first-max tie-breaking (contiguous mapping:
// lane l owns [16l, 16l+16); lower lane == lower indices).
// R6-R10 evidence: scalar float arrays / named scalars never fully promote
// (VGPR stuck 48-68; memory-homed re-reads each iter). But float4/ext-vector
// locals DO promote (wave_layer: VGPR 136). So v9 holds the 16 points as 16
// named float4 locals + 4 float4 dist regs, staged via a padded LDS float4
// array (per-lane stride 17 units -> b128 quad (l+r)%8 cycles all 8 bank
// quads: conflict-free even if the compiler chooses to re-read per iter).
// Reduce = R6's proven structure: per-lane (bv,bi) scan, DPP fmax, ballot ->
// lowest tied lane writes u64 key (bv_bits<<32 | ~bi), parity-buffered key
// slots, ONE barrier, all threads b128-scan 4 keys, far = bi, centroid via
// one broadcast ds_read_b128 from the padded array.
// ---------------------------------------------------------------------------
template <int CTRL>
__device__ __forceinline__ float dpp_fmax_step(float v) {
  const int t = __builtin_amdgcn_update_dpp(0, __float_as_int(v), CTRL, 0xf, 0xf, true);
  return fmaxf(v, __int_as_float(t));
}

__global__ __launch_bounds__(256, 1) void fps_kernel(const float4* __restrict__ pts4,
                                                     float* __restrict__ new_xyz) {
  const int b   = blockIdx.x;
  const int tid = threadIdx.x;
  __shared__ float4 plds[256 * 17];                    // padded: lane stride 17
  __shared__ alignas(16) unsigned long long s_keys[8]; // [parity*4 + wave]

  const float4* pb = pts4 + (size_t)b * NPTS;
  const int t17 = tid * 17;
#pragma unroll
  for (int r = 0; r < 16; ++r) plds[t17 + r] = pb[tid * 16 + r];
  __syncthreads();

  // 16 named float4 locals (promotable vector shape) + 4 float4 dist regs
#define DECLQ(i) float4 q##i = plds[t17 + i];
  DECLQ(0) DECLQ(1) DECLQ(2) DECLQ(3) DECLQ(4) DECLQ(5) DECLQ(6) DECLQ(7)
  DECLQ(8) DECLQ(9) DECLQ(10) DECLQ(11) DECLQ(12) DECLQ(13) DECLQ(14) DECLQ(15)
#undef DECLQ
  float4 dd0 = make_float4(1e10f, 1e10f, 1e10f, 1e10f);
  float4 dd1 = dd0, dd2 = dd0, dd3 = dd0;

  float4 C0 = plds[0];
  float cx = C0.x, cy = C0.y, cz = C0.z;

  const int wid  = tid >> 6;
  const int lane = tid & 63;
  const int base = tid * 16;
  for (int j = 0; j < NS; ++j) {
    if (tid == 0) {
      float* o = new_xyz + ((size_t)b * NS + j) * 3;
      o[0] = cx; o[1] = cy; o[2] = cz;
    }
    float bv = -1.0f;
    int   bi = 0;
    // forward scan, strict > : keeps FIRST (smallest-index) max
#define STEP(i, D, Cm)                                                         \
  {                                                                            \
    const float dx = __fsub_rn(q##i.x, cx);                                    \
    const float dy = __fsub_rn(q##i.y, cy);                                    \
    const float dz = __fsub_rn(q##i.z, cz);                                    \
    const float d  = __fadd_rn(__fadd_rn(__fmul_rn(dx, dx), __fmul_rn(dy, dy)),\
                               __fmul_rn(dz, dz));                             \
    const float nd = fminf(D.Cm, d);                                           \
    D.Cm = nd;                                                                 \
    const bool m = nd > bv;                                                    \
    bv = m ? nd : bv;                                                          \
    bi = m ? (base + i) : bi;                                                  \
  }
    STEP(0, dd0, x) STEP(1, dd0, y) STEP(2, dd0, z) STEP(3, dd0, w)
    STEP(4, dd1, x) STEP(5, dd1, y) STEP(6, dd1, z) STEP(7, dd1, w)
    STEP(8, dd2, x) STEP(9, dd2, y) STEP(10, dd2, z) STEP(11, dd2, w)
    STEP(12, dd3, x) STEP(13, dd3, y) STEP(14, dd3, z) STEP(15, dd3, w)
#undef STEP
    // wave max via DPP (VALU-latency chain, no DS unit)
    float v = bv;
    v = dpp_fmax_step<0x111>(v);   // row_shr:1
    v = dpp_fmax_step<0x112>(v);   // row_shr:2
    v = dpp_fmax_step<0x114>(v);   // row_shr:4
    v = dpp_fmax_step<0x118>(v);   // row_shr:8
    v = dpp_fmax_step<0x142>(v);   // row_bcast:15
    v = dpp_fmax_step<0x143>(v);   // row_bcast:31
    const float wmax = __int_as_float(
        __builtin_amdgcn_readlane(__float_as_int(v), 63));
    const unsigned long long cand = __ballot(bv == wmax);
    const int fl = (int)__ffsll((long long)cand) - 1;  // lowest lane = smallest idx
    const int par = (j & 1) * 4;
    if (lane == fl)
      keys_write:
      s_keys[par + wid] = ((unsigned long long)__float_as_uint(wmax) << 32) |
                          (unsigned)(~bi);
    __syncthreads();
    // flat 4-key scan: two b128 loads, 3 u64 maxes
    const ullx2 ka = *(const ullx2*)(s_keys + par);
    const ullx2 kb = *(const ullx2*)(s_keys + par + 2);
    unsigned long long k = ka.x;
    if (ka.y > k) k = ka.y;
    if (kb.x > k) k = kb.x;
    if (kb.y > k) k = kb.y;
    const int far = (int)(~(unsigned)k) & 0xFFF;
    // centroid: one broadcast b128 from the padded slot of point `far`
    const float4 C = plds[(far >> 4) * 17 + (far & 15)];
    cx = C.x; cy = C.y; cz = C.z;
  }
}

// ---------------------------------------------------------------------------
// Ball grouping, all three radii in one index-ordered scan. One wave per (b,s).
// Reads precomputed (x,y,z,|p|^2) float4: one coalesced 16B load per point.
// ---------------------------------------------------------------------------
__global__ __launch_bounds__(64) void group_kernel(
    const float4* __restrict__ pts4, const float* __restrict__ new_xyz,
    int* __restrict__ nbr0, int* __restrict__ nbr1, int* __restrict__ nbr2,
    int* __restrict__ cnt0, int* __restrict__ cnt1, int* __restrict__ cnt2) {
  const int bs   = blockIdx.x;
  const int b    = bs >> 10;
  const int lane = threadIdx.x;
  const float r2_0 = (float)(0.1 * 0.1);
  const float r2_1 = (float)(0.2 * 0.2);
  const float r2_2 = (float)(0.4 * 0.4);

  const float cx = new_xyz[bs * 3 + 0];
  const float cy = new_xyz[bs * 3 + 1];
  const float cz = new_xyz[bs * 3 + 2];
  const float sn = __fadd_rn(__fadd_rn(__fmul_rn(cx, cx), __fmul_rn(cy, cy)),
                             __fmul_rn(cz, cz));
  const float4* pb = pts4 + (size_t)b * NPTS;
  const unsigned long long below = (1ull << lane) - 1ull;

  int c0 = 0, c1 = 0, c2 = 0;
  for (int base = 0; base < NPTS; base += 64) {
    const int p = base + lane;
    const float4 P = pb[p];
    const float dt = __fadd_rn(__fadd_rn(__fmul_rn(cx, P.x), __fmul_rn(cy, P.y)),
                               __fmul_rn(cz, P.z));
    const float sqd = __fsub_rn(__fadd_rn(sn, P.w), __fmul_rn(2.0f, dt));
    const bool in0 = (sqd <= r2_0);
    const bool in1 = (sqd <= r2_1);
    const bool in2 = (sqd <= r2_2);
    const unsigned long long m0 = __ballot(in0);
    const unsigned long long m1 = __ballot(in1);
    const unsigned long long m2 = __ballot(in2);
    if (c0 < 16) {
      const int slot = c0 + __popcll(m0 & below);
      if (in0 && slot < 16) nbr0[bs * 16 + slot] = p;
      c0 = min(c0 + __popcll(m0), 16);
    }
    if (c1 < 32) {
      const int slot = c1 + __popcll(m1 & below);
      if (in1 && slot < 32) nbr1[bs * 32 + slot] = p;
      c1 = min(c1 + __popcll(m1), 32);
    }
    if (c2 < 128) {
      const int slot = c2 + __popcll(m2 & below);
      if (in2 && slot < 128) nbr2[bs * 128 + slot] = p;
      c2 = min(c2 + __popcll(m2), 128);
    }
    if (c0 == 16 && c1 == 32 && c2 == 128) break;
  }
  if (lane == 0) {
    cnt0[bs] = c0;
    cnt1[bs] = c1;
    cnt2[bs] = c2;
  }
}

// ---------------------------------------------------------------------------
// One layer for one wave: RT row-tiles (16 rows each) x all CO cols, K-chunks
// of 32. A from LDS (rows = this wave's neighbors), B fragments from global
// (pre-packed). Non-last: relu -> bf16 LDS store. Last: per-lane column max.
// ---------------------------------------------------------------------------
template <int RT, int KC, int CO, int SIN, int SOUT, bool LAST>
__device__ __forceinline__ void wave_layer(const __bf16* in, __bf16* outb,
                                           const __bf16* __restrict__ wf,
                                           const float* __restrict__ bias,
                                           int lane, float* colmax) {
  bf16x8 a[RT][KC];
#pragma unroll
  for (int rt = 0; rt < RT; ++rt)
#pragma unroll
    for (int kc = 0; kc < KC; ++kc)
      a[rt][kc] = *(const bf16x8*)(in + (rt * 16 + (lane & 15)) * SIN + kc * 32 +
                                   (lane >> 4) * 8);
#pragma unroll
  for (int ct = 0; ct < CO / 16; ++ct) {
    const float bv = bias[ct * 16 + (lane & 15)];
    bf16x8 bfr[KC];
#pragma unroll
    for (int kc = 0; kc < KC; ++kc)
      bfr[kc] = *(const bf16x8*)(wf + ((size_t)(ct * KC + kc) * 64 + lane) * 8);
    float cm = 0.0f;
#pragma unroll
    for (int rt = 0; rt < RT; ++rt) {
      f32x4 acc = {0.0f, 0.0f, 0.0f, 0.0f};
#pragma unroll
      for (int kc = 0; kc < KC; ++kc)
        acc = __builtin_amdgcn_mfma_f32_16x16x32_bf16(a[rt][kc], bfr[kc], acc, 0, 0, 0);
      if constexpr (!LAST) {
#pragma unroll
        for (int r = 0; r < 4; ++r) {
          const int row = rt * 16 + (lane >> 4) * 4 + r;
          const float v = fmaxf(acc[r] + bv, 0.0f);
          outb[row * SOUT + ct * 16 + (lane & 15)] = (__bf16)v;
        }
      } else {
#pragma unroll
        for (int r = 0; r < 4; ++r) cm = fmaxf(cm, acc[r] + bv);
      }
    }
    if constexpr (LAST) colmax[ct] = fmaxf(colmax[ct], cm);
  }
}

// ---------------------------------------------------------------------------
// Fused gather + 3-layer MFMA MLP + max-pool.
// WPP waves per point, PPB points per block. Row-slices are wave-private
// through gather/L1/L2/L3, so no barriers except the final cross-wave max
// (WPP>1 only; requires SH2==SX so h2 overlays the wave's own X rows).
// LDS row strides C+8 (stride%16==8 elems): 2-way bank alias only, 16B aligned.
// ---------------------------------------------------------------------------
template <int K, int C1, int C2, int C3, int WPP, int PPB>
__global__ __launch_bounds__(64 * WPP * PPB) void mlp_mfma(
    const float4* __restrict__ pts4, const float* __restrict__ feat,
    const float* __restrict__ new_xyz,
    const int* __restrict__ nbr, const int* __restrict__ cnt_arr,
    const __bf16* __restrict__ wf1, const float* __restrict__ b1,
    const __bf16* __restrict__ wf2, const float* __restrict__ b2,
    const __bf16* __restrict__ wf3, const float* __restrict__ b3,
    float* __restrict__ out, int ch_off) {
  constexpr int SX  = 104;           // 67 in-ch, zero-pad to 96, stride 104
  constexpr int SH1 = C1 + 8;
  constexpr int SH2 = C2 + 8;
  constexpr int KC1 = 3;
  constexpr int KC2 = C1 / 32;
  constexpr int KC3 = C2 / 32;
  constexpr int PT  = (104 + SH1) * K;   // region0 (X/h2 overlay) + region1 (h1)
  constexpr int MW  = K / WPP;
  constexpr int RT  = MW / 16;
  static_assert(WPP == 1 || SH2 == SX, "h2 overlay must match X rows for WPP>1");
  __shared__ __bf16 lds[PPB * PT];
  __shared__ float  red[(WPP > 1) ? WPP * C3 : 1];

  const int tid  = threadIdx.x;
  const int lane = tid & 63;
  const int wid  = tid >> 6;

  // ---- gather: stage X rows (3 rel coords + 64 feats + zero pad) as bf16 ----
  constexpr int TPN = (64 * WPP) / K;   // threads per neighbor (4, 2, 2)
  constexpr int FPT = NF / TPN;         // features per thread
  {
    const int ln = tid / TPN;
    const int s  = tid - ln * TPN;
    const int lp = ln / K;
    const int n  = ln - lp * K;
    const int p  = blockIdx.x * PPB + lp;
    const int b  = p >> 10;
    const int cnt = cnt_arr[p];
    const int idx = nbr[p * K + min(n, cnt - 1)];
    __bf16* Xr = lds + lp * PT + n * SX;
    const float4* fp4 = (const float4*)(feat + ((size_t)b * NPTS + idx) * NF + s * FPT);
#pragma unroll
    for (int j = 0; j < FPT / 4; ++j) {
      const float4 v = fp4[j];
      Xr[3 + s * FPT + 4 * j + 0] = (__bf16)v.x;
      Xr[3 + s * FPT + 4 * j + 1] = (__bf16)v.y;
      Xr[3 + s * FPT + 4 * j + 2] = (__bf16)v.z;
      Xr[3 + s * FPT + 4 * j + 3] = (__bf16)v.w;
    }
    if (s == 0) {
      const float4 P = pts4[(size_t)b * NPTS + idx];
      Xr[0] = (__bf16)(P.x - new_xyz[p * 3 + 0]);
      Xr[1] = (__bf16)(P.y - new_xyz[p * 3 + 1]);
      Xr[2] = (__bf16)(P.z - new_xyz[p * 3 + 2]);
#pragma unroll
      for (int k = 67; k < 96; ++k) Xr[k] = (__bf16)0.0f;
    }
  }

  // ---- per-wave 3-layer pipeline on its own row slice ----
  const int lpg = wid / WPP;
  const int wv  = wid - lpg * WPP;
  const int p   = blockIdx.x * PPB + lpg;
  const __bf16* X  = lds + lpg * PT + wv * MW * SX;
  __bf16*       H1 = lds + lpg * PT + K * 104 + wv * MW * SH1;
  __bf16*       H2 = lds + lpg * PT + wv * MW * SH2;

  float colmax[C3 / 16];
#pragma unroll
  for (int ct = 0; ct < C3 / 16; ++ct) colmax[ct] = 0.0f;

  wave_layer<RT, KC1, C1, SX, SH1, false>(X, H1, wf1, b1, lane, nullptr);
  wave_layer<RT, KC2, C2, SH1, SH2, false>(H1, H2, wf2, b2, lane, nullptr);
  wave_layer<RT, KC3, C3, SH2, 0, true>(H2, nullptr, wf3, b3, lane, colmax);

  // quad-reduce: combine the 4 row-quads of the wave
#pragma unroll
  for (int ct = 0; ct < C3 / 16; ++ct) {
    float v = colmax[ct];
    v = fmaxf(v, __shfl_xor(v, 16));
    v = fmaxf(v, __shfl_xor(v, 32));
    colmax[ct] = v;
  }

  if constexpr (WPP == 1) {
    if (lane < 16) {
      float* op = out + (size_t)p * 320 + ch_off;
#pragma unroll
      for (int ct = 0; ct < C3 / 16; ++ct) op[ct * 16 + lane] = colmax[ct];
    }
  } else {
    if (lane < 16) {
#pragma unroll
      for (int ct = 0; ct < C3 / 16; ++ct)
        red[wv * C3 + ct * 16 + lane] = colmax[ct];
    }
    __syncthreads();
    if (tid < C3) {
      float v = red[tid];
#pragma unroll
      for (int w = 1; w < WPP; ++w) v = fmaxf(v, red[w * C3 + tid]);
      out[(size_t)p * 320 + ch_off + tid] = v;
    }
  }
}

// ---------------------------------------------------------------------------
// Workspace (int units):
//   [0, 24576)          packed bf16 weight fragments (49152 bf16 = 98304 B)
//   [24576, 32768)      cnt0   [32768,40960) cnt1   [40960,49152) cnt2
//   [49152, 180224)     nbr0   [180224,442368) nbr1  [442368,1490944) nbr2
//   [1490944, 1622016)  pts4 (32768 x float4)        total ~6.49 MB
// ---------------------------------------------------------------------------
extern "C" void kernel_launch(void* const* d_in, const int* in_sizes, int n_in,
                              void* d_out, int out_size, void* d_ws, size_t ws_size,
                              hipStream_t stream) {
  const float* xyz  = (const float*)d_in[0];
  const float* feat = (const float*)d_in[1];
  float* out      = (float*)d_out;
  float* new_xyz  = out;
  float* feat_out = out + 24576;

  __bf16* wsb = (__bf16*)d_ws;
  int*    wsi = (int*)d_ws;

  // weight fragment offsets (bf16 elems)
  const int OW[9] = {0, 3072, 4096, 6144, 12288, 16384, 24576, 30720, 36864};
  const int widx[9] = {2, 4, 6, 8, 10, 12, 14, 16, 18};
  const int co[9] = {32, 32, 64, 64, 64, 128, 64, 96, 128};
  const int ci[9] = {67, 32, 32, 67, 64, 64, 67, 64, 96};
  const int kc[9] = {3, 1, 1, 3, 2, 2, 3, 2, 3};
  WPrep wp;
  for (int i = 0; i < 9; ++i) {
    wp.src[i] = (const float*)d_in[widx[i]];
    wp.CO[i] = co[i]; wp.CI[i] = ci[i]; wp.KC[i] = kc[i]; wp.off[i] = OW[i];
  }
  wprep_kernel<<<dim3(6, 9), 256, 0, stream>>>(wp, wsb);

  float4* pts4 = (float4*)(wsi + 1490944);
  pts_prep<<<(NB * NPTS + 255) / 256, 256, 0, stream>>>(xyz, pts4);

  fps_kernel<<<NB, 256, 0, stream>>>(pts4, new_xyz);

  int* cnt0 = wsi + 24576;
  int* cnt1 = wsi + 32768;
  int* cnt2 = wsi + 40960;
  int* nbr0 = wsi + 49152;
  int* nbr1 = wsi + 180224;
  int* nbr2 = wsi + 442368;
  group_kernel<<<NB * NS, 64, 0, stream>>>(pts4, new_xyz, nbr0, nbr1, nbr2,
                                           cnt0, cnt1, cnt2);

  mlp_mfma<16, 32, 32, 64, 1, 4><<<NB * NS / 4, 256, 0, stream>>>(
      pts4, feat, new_xyz, nbr0, cnt0,
      wsb + OW[0], (const float*)d_in[3],
      wsb + OW[1], (const float*)d_in[5],
      wsb + OW[2], (const float*)d_in[7],
      feat_out, 0);
  mlp_mfma<32, 64, 64, 128, 1, 2><<<NB * NS / 2, 128, 0, stream>>>(
      pts4, feat, new_xyz, nbr1, cnt1,
      wsb + OW[3], (const float*)d_in[9],
      wsb + OW[4], (const float*)d_in[11],
      wsb + OW[5], (const float*)d_in[13],
      feat_out, 64);
  mlp_mfma<128, 64, 96, 128, 4, 1><<<NB * NS, 256, 0, stream>>>(
      pts4, feat, new_xyz, nbr2, cnt2,
      wsb + OW[6], (const float*)d_in[15],
      wsb + OW[7], (const float*)d_in[17],
      wsb + OW[8], (const float*)d_in[19],
      feat_out, 192);
}